// Round 1
// baseline (230.011 us; speedup 1.0000x reference)
//
#include <hip/hip_runtime.h>
#include <hip/hip_bf16.h>

// Problem dims
#define BROWS 8192
#define IDIM 256
#define HDIM 512
#define KCAT 768    // I + H
#define G4 2048     // 4*H

typedef __bf16 bf16_t;
typedef bf16_t bf16x8 __attribute__((ext_vector_type(8)));
typedef float f32x4 __attribute__((ext_vector_type(4)));

__device__ __forceinline__ f32x4 mfma16(bf16x8 a, bf16x8 b, f32x4 c) {
    return __builtin_amdgcn_mfma_f32_16x16x32_bf16(a, b, c, 0, 0, 0);
}

__device__ __forceinline__ ushort f2bf(float f) {
    union { float f; unsigned u; } v; v.f = f;
    unsigned u = v.u;
    unsigned r = (u + 0x7fffu + ((u >> 16) & 1u)) >> 16;  // RNE, inputs finite
    return (ushort)r;
}

__device__ __forceinline__ float sigmoidf_(float x) {
    return 1.f / (1.f + __expf(-x));
}
__device__ __forceinline__ float tanhf_(float x) {
    // 1 - 2/(e^{2x}+1): safe at +/-inf (no inf/inf)
    return 1.f - 2.f / (__expf(2.f * x) + 1.f);
}

// ---------------- prep: fp32 -> bf16 packing ----------------
// regions: xh[B,768]=[x|h], aw0[256,768], aw1[256,256], wcat[2048,768]=[w_ih|w_hh], ow0[512,512]
__global__ void __launch_bounds__(256) prep_kernel(
        const float* __restrict__ x, const float* __restrict__ h,
        const float* __restrict__ aw0, const float* __restrict__ aw1,
        const float* __restrict__ w_ih, const float* __restrict__ w_hh,
        const float* __restrict__ ow0,
        ushort* __restrict__ xh, ushort* __restrict__ baw0,
        ushort* __restrict__ baw1, ushort* __restrict__ wcat,
        ushort* __restrict__ bow0) {
    int idx = blockIdx.x * 256 + threadIdx.x;
    const int N_XH = BROWS * KCAT;      // 6291456
    const int N_AW0 = IDIM * KCAT;      // 196608
    const int N_AW1 = IDIM * IDIM;      // 65536
    const int N_WCAT = G4 * KCAT;       // 1572864
    const int N_OW0 = HDIM * HDIM;      // 262144
    if (idx < N_XH) {
        int b = idx / KCAT, k = idx - b * KCAT;
        float v = (k < IDIM) ? x[b * IDIM + k] : h[b * HDIM + (k - IDIM)];
        xh[idx] = f2bf(v);
        return;
    }
    idx -= N_XH;
    if (idx < N_AW0) { baw0[idx] = f2bf(aw0[idx]); return; }
    idx -= N_AW0;
    if (idx < N_AW1) { baw1[idx] = f2bf(aw1[idx]); return; }
    idx -= N_AW1;
    if (idx < N_WCAT) {
        int o = idx / KCAT, k = idx - o * KCAT;
        float v = (k < IDIM) ? w_ih[o * IDIM + k] : w_hh[o * HDIM + (k - IDIM)];
        wcat[idx] = f2bf(v);
        return;
    }
    idx -= N_WCAT;
    if (idx < N_OW0) { bow0[idx] = f2bf(ow0[idx]); }
}

// ---------------- a0 = relu(xh @ aw0^T + ab0), bf16 out ----------------
// M=8192 N=256 K=768. block 64x64 (4 waves 2x2), wave 32x32.
__global__ void __launch_bounds__(256) a0_gemm(
        const ushort* __restrict__ A, const ushort* __restrict__ W,
        const float* __restrict__ bias, ushort* __restrict__ outp) {
    const int lane = threadIdx.x & 63;
    const int wave = threadIdx.x >> 6;
    const int wm = wave >> 1, wn = wave & 1;
    const int row0 = blockIdx.x * 64 + wm * 32;
    const int col0 = blockIdx.y * 64 + wn * 32;
    const int r = lane & 15, g = lane >> 4;
    const int koff = g * 8;
    f32x4 acc[2][2] = {};
#pragma unroll 4
    for (int kk = 0; kk < KCAT; kk += 32) {
        bf16x8 a0f = *(const bf16x8*)&A[(row0 + r) * KCAT + kk + koff];
        bf16x8 a1f = *(const bf16x8*)&A[(row0 + 16 + r) * KCAT + kk + koff];
        bf16x8 b0f = *(const bf16x8*)&W[(col0 + r) * KCAT + kk + koff];
        bf16x8 b1f = *(const bf16x8*)&W[(col0 + 16 + r) * KCAT + kk + koff];
        acc[0][0] = mfma16(a0f, b0f, acc[0][0]);
        acc[0][1] = mfma16(a0f, b1f, acc[0][1]);
        acc[1][0] = mfma16(a1f, b0f, acc[1][0]);
        acc[1][1] = mfma16(a1f, b1f, acc[1][1]);
    }
#pragma unroll
    for (int tm = 0; tm < 2; tm++)
#pragma unroll
    for (int tn = 0; tn < 2; tn++) {
        int col = col0 + tn * 16 + r;
        float bv = bias[col];
#pragma unroll
        for (int reg = 0; reg < 4; reg++) {
            int row = row0 + tm * 16 + g * 4 + reg;
            float v = acc[tm][tn][reg] + bv;
            outp[row * IDIM + col] = f2bf(v > 0.f ? v : 0.f);
        }
    }
}

// ---------------- logits = a0 @ aw1^T + ab1, fp32 out ----------------
// M=8192 N=256 K=256
__global__ void __launch_bounds__(256) logits_gemm(
        const ushort* __restrict__ A, const ushort* __restrict__ W,
        const float* __restrict__ bias, float* __restrict__ outp) {
    const int lane = threadIdx.x & 63;
    const int wave = threadIdx.x >> 6;
    const int wm = wave >> 1, wn = wave & 1;
    const int row0 = blockIdx.x * 64 + wm * 32;
    const int col0 = blockIdx.y * 64 + wn * 32;
    const int r = lane & 15, g = lane >> 4;
    const int koff = g * 8;
    f32x4 acc[2][2] = {};
#pragma unroll
    for (int kk = 0; kk < IDIM; kk += 32) {
        bf16x8 a0f = *(const bf16x8*)&A[(row0 + r) * IDIM + kk + koff];
        bf16x8 a1f = *(const bf16x8*)&A[(row0 + 16 + r) * IDIM + kk + koff];
        bf16x8 b0f = *(const bf16x8*)&W[(col0 + r) * IDIM + kk + koff];
        bf16x8 b1f = *(const bf16x8*)&W[(col0 + 16 + r) * IDIM + kk + koff];
        acc[0][0] = mfma16(a0f, b0f, acc[0][0]);
        acc[0][1] = mfma16(a0f, b1f, acc[0][1]);
        acc[1][0] = mfma16(a1f, b0f, acc[1][0]);
        acc[1][1] = mfma16(a1f, b1f, acc[1][1]);
    }
#pragma unroll
    for (int tm = 0; tm < 2; tm++)
#pragma unroll
    for (int tn = 0; tn < 2; tn++) {
        int col = col0 + tn * 16 + r;
        float bv = bias[col];
#pragma unroll
        for (int reg = 0; reg < 4; reg++) {
            int row = row0 + tm * 16 + g * 4 + reg;
            outp[row * IDIM + col] = acc[tm][tn][reg] + bv;
        }
    }
}

// ---------------- rowwise softmax + attn out + x_att into xh ----------------
__global__ void __launch_bounds__(256) attn_softmax(
        const float* __restrict__ logits, const float* __restrict__ x,
        float* __restrict__ attn_out, ushort* __restrict__ xh) {
    const int wave = threadIdx.x >> 6, lane = threadIdx.x & 63;
    const int row = blockIdx.x * 4 + wave;
    float v[4];
    float m = -1e30f;
#pragma unroll
    for (int i = 0; i < 4; i++) {
        v[i] = logits[row * IDIM + i * 64 + lane];
        m = fmaxf(m, v[i]);
    }
#pragma unroll
    for (int s = 32; s; s >>= 1) m = fmaxf(m, __shfl_xor(m, s, 64));
    float sum = 0.f;
#pragma unroll
    for (int i = 0; i < 4; i++) { v[i] = __expf(v[i] - m); sum += v[i]; }
#pragma unroll
    for (int s = 32; s; s >>= 1) sum += __shfl_xor(sum, s, 64);
    float inv = 1.f / sum;
#pragma unroll
    for (int i = 0; i < 4; i++) {
        int idx = i * 64 + lane;
        float a = v[i] * inv;
        attn_out[row * IDIM + idx] = a;
        xh[row * KCAT + idx] = f2bf(x[row * IDIM + idx] * a);
    }
}

// ---------------- gates GEMM + LSTM epilogue ----------------
// gates = [x_att|h] @ [w_ih|w_hh]^T : M=8192, N(j)=512, 4 gate groups, K=768
__global__ void __launch_bounds__(256) gates_gemm(
        const ushort* __restrict__ A, const ushort* __restrict__ W,
        const float* __restrict__ b_ih, const float* __restrict__ b_hh,
        const float* __restrict__ c_in,
        float* __restrict__ h_out, float* __restrict__ c_out,
        ushort* __restrict__ h_bf) {
    const int lane = threadIdx.x & 63;
    const int wave = threadIdx.x >> 6;
    const int wm = wave >> 1, wn = wave & 1;
    const int row0 = blockIdx.x * 64 + wm * 32;
    const int col0 = blockIdx.y * 64 + wn * 32;   // hidden j
    const int r = lane & 15, g = lane >> 4;
    const int koff = g * 8;
    f32x4 acc[4][2][2] = {};
    for (int kk = 0; kk < KCAT; kk += 32) {
        bf16x8 af0 = *(const bf16x8*)&A[(row0 + r) * KCAT + kk + koff];
        bf16x8 af1 = *(const bf16x8*)&A[(row0 + 16 + r) * KCAT + kk + koff];
#pragma unroll
        for (int gi = 0; gi < 4; gi++) {
            bf16x8 bf0 = *(const bf16x8*)&W[(gi * HDIM + col0 + r) * KCAT + kk + koff];
            bf16x8 bf1 = *(const bf16x8*)&W[(gi * HDIM + col0 + 16 + r) * KCAT + kk + koff];
            acc[gi][0][0] = mfma16(af0, bf0, acc[gi][0][0]);
            acc[gi][0][1] = mfma16(af0, bf1, acc[gi][0][1]);
            acc[gi][1][0] = mfma16(af1, bf0, acc[gi][1][0]);
            acc[gi][1][1] = mfma16(af1, bf1, acc[gi][1][1]);
        }
    }
#pragma unroll
    for (int tm = 0; tm < 2; tm++)
#pragma unroll
    for (int tn = 0; tn < 2; tn++) {
        int j = col0 + tn * 16 + r;
        float bi = b_ih[j] + b_hh[j];
        float bff = b_ih[HDIM + j] + b_hh[HDIM + j];
        float bg = b_ih[2 * HDIM + j] + b_hh[2 * HDIM + j];
        float bo = b_ih[3 * HDIM + j] + b_hh[3 * HDIM + j];
#pragma unroll
        for (int reg = 0; reg < 4; reg++) {
            int row = row0 + tm * 16 + g * 4 + reg;
            float ig = sigmoidf_(acc[0][tm][tn][reg] + bi);
            float fg = sigmoidf_(acc[1][tm][tn][reg] + bff);
            float gg = tanhf_(acc[2][tm][tn][reg] + bg);
            float og = sigmoidf_(acc[3][tm][tn][reg] + bo);
            float cn = fg * c_in[row * HDIM + j] + ig * gg;
            float hn = og * tanhf_(cn);
            c_out[row * HDIM + j] = cn;
            h_out[row * HDIM + j] = hn;
            h_bf[row * HDIM + j] = f2bf(hn);
        }
    }
}

// ---------------- head: relu(h_new @ ow0^T + ob0) -> dot ow1 -> sigmoid ----------------
// block tile 32 rows x 512 cols (4 waves, each 32x128). M=8192, K=512.
__global__ void __launch_bounds__(256) head_kernel(
        const ushort* __restrict__ A, const ushort* __restrict__ W,
        const float* __restrict__ ob0, const float* __restrict__ ow1,
        const float* __restrict__ ob1, float* __restrict__ outp) {
    const int lane = threadIdx.x & 63;
    const int wave = threadIdx.x >> 6;
    const int row0 = blockIdx.x * 32;
    const int col0 = wave * 128;
    const int r = lane & 15, g = lane >> 4;
    const int koff = g * 8;
    f32x4 acc[2][8] = {};
    for (int kk = 0; kk < HDIM; kk += 32) {
        bf16x8 af0 = *(const bf16x8*)&A[(row0 + r) * HDIM + kk + koff];
        bf16x8 af1 = *(const bf16x8*)&A[(row0 + 16 + r) * HDIM + kk + koff];
#pragma unroll
        for (int tn = 0; tn < 8; tn++) {
            bf16x8 bf = *(const bf16x8*)&W[(col0 + tn * 16 + r) * HDIM + kk + koff];
            acc[0][tn] = mfma16(af0, bf, acc[0][tn]);
            acc[1][tn] = mfma16(af1, bf, acc[1][tn]);
        }
    }
    float part[2][4] = {};
#pragma unroll
    for (int tn = 0; tn < 8; tn++) {
        int cix = col0 + tn * 16 + r;
        float b0 = ob0[cix], w1 = ow1[cix];
#pragma unroll
        for (int tm = 0; tm < 2; tm++)
#pragma unroll
            for (int reg = 0; reg < 4; reg++) {
                float v = acc[tm][tn][reg] + b0;
                v = v > 0.f ? v : 0.f;
                part[tm][reg] += v * w1;
            }
    }
    __shared__ float lds[32][4];
#pragma unroll
    for (int tm = 0; tm < 2; tm++)
#pragma unroll
        for (int reg = 0; reg < 4; reg++) {
            float p = part[tm][reg];
            p += __shfl_xor(p, 1, 64);
            p += __shfl_xor(p, 2, 64);
            p += __shfl_xor(p, 4, 64);
            p += __shfl_xor(p, 8, 64);
            if (r == 0) lds[tm * 16 + g * 4 + reg][wave] = p;
        }
    __syncthreads();
    int t = threadIdx.x;
    if (t < 32) {
        float s = lds[t][0] + lds[t][1] + lds[t][2] + lds[t][3] + ob1[0];
        outp[row0 + t] = 1.f / (1.f + __expf(-s));
    }
}

extern "C" void kernel_launch(void* const* d_in, const int* in_sizes, int n_in,
                              void* d_out, int out_size, void* d_ws, size_t ws_size,
                              hipStream_t stream) {
    const float* x    = (const float*)d_in[0];
    const float* h    = (const float*)d_in[1];
    const float* c    = (const float*)d_in[2];
    const float* aw0  = (const float*)d_in[3];
    const float* ab0  = (const float*)d_in[4];
    const float* aw1  = (const float*)d_in[5];
    const float* ab1  = (const float*)d_in[6];
    const float* w_ih = (const float*)d_in[7];
    const float* b_ih = (const float*)d_in[8];
    const float* w_hh = (const float*)d_in[9];
    const float* b_hh = (const float*)d_in[10];
    const float* ow0  = (const float*)d_in[11];
    const float* ob0  = (const float*)d_in[12];
    const float* ow1  = (const float*)d_in[13];
    const float* ob1  = (const float*)d_in[14];

    char* ws = (char*)d_ws;
    ushort* xh     = (ushort*)(ws + 0);           // 8192*768*2  = 12582912
    ushort* a0     = (ushort*)(ws + 12582912);    // 8192*256*2  = 4194304
    float*  logits = (float*) (ws + 16777216);    // 8192*256*4  = 8388608
    ushort* hbf    = (ushort*)(ws + 25165824);    // 8192*512*2  = 8388608
    ushort* baw0   = (ushort*)(ws + 33554432);    // 256*768*2   = 393216
    ushort* baw1   = (ushort*)(ws + 33947648);    // 256*256*2   = 131072
    ushort* wcat   = (ushort*)(ws + 34078720);    // 2048*768*2  = 3145728
    ushort* bow0   = (ushort*)(ws + 37224448);    // 512*512*2   = 524288
    // total ws use: 37748736 bytes

    float* outv    = (float*)d_out;               // [8192]
    float* h_out   = outv + 8192;                 // [8192,512]
    float* c_out   = outv + 4202496;              // [8192,512]
    float* attn_o  = outv + 8396800;              // [8192,256]

    prep_kernel<<<32768, 256, 0, stream>>>(x, h, aw0, aw1, w_ih, w_hh, ow0,
                                           xh, baw0, baw1, wcat, bow0);
    a0_gemm<<<dim3(128, 4), 256, 0, stream>>>(xh, baw0, ab0, a0);
    logits_gemm<<<dim3(128, 4), 256, 0, stream>>>(a0, baw1, ab1, logits);
    attn_softmax<<<2048, 256, 0, stream>>>(logits, x, attn_o, xh);
    gates_gemm<<<dim3(128, 8), 256, 0, stream>>>(xh, wcat, b_ih, b_hh, c,
                                                 h_out, c_out, hbf);
    head_kernel<<<256, 256, 0, stream>>>(hbf, bow0, ob0, ow1, ob1, outv);
}

// Round 2
// 120.411 us; speedup vs baseline: 1.9102x; 1.9102x over previous
//
#include <hip/hip_runtime.h>
#include <hip/hip_bf16.h>

// Problem dims
#define BROWS 8192
#define IDIM 256
#define HDIM 512
#define KCAT 768    // I + H
#define G4 2048     // 4*H

typedef __bf16 bf16_t;
typedef bf16_t bf16x8 __attribute__((ext_vector_type(8)));
typedef float f32x4 __attribute__((ext_vector_type(4)));

__device__ __forceinline__ f32x4 mfma16(bf16x8 a, bf16x8 b, f32x4 c) {
    return __builtin_amdgcn_mfma_f32_16x16x32_bf16(a, b, c, 0, 0, 0);
}

__device__ __forceinline__ ushort f2bf(float f) {
    union { float f; unsigned u; } v; v.f = f;
    unsigned u = v.u;
    unsigned r = (u + 0x7fffu + ((u >> 16) & 1u)) >> 16;  // RNE, inputs finite
    return (ushort)r;
}

__device__ __forceinline__ float bf2f(ushort u) {
    union { unsigned u; float f; } v; v.u = (unsigned)u << 16; return v.f;
}

__device__ __forceinline__ float sigmoidf_(float x) {
    return 1.f / (1.f + __expf(-x));
}
__device__ __forceinline__ float tanhf_(float x) {
    return 1.f - 2.f / (__expf(2.f * x) + 1.f);   // safe at +/-inf
}

// async global -> LDS, 16 bytes per lane (lds dest: wave-uniform base + lane*16)
typedef __attribute__((address_space(1))) const unsigned gas_u32;
typedef __attribute__((address_space(3))) unsigned las_u32;
__device__ __forceinline__ void gld_lds16(const void* g, void* l) {
    __builtin_amdgcn_global_load_lds((gas_u32*)g, (las_u32*)l, 16, 0, 0);
}

// ---------------- prep: fp32 -> bf16 packing (float4 vectorized) ----------------
// regions: xh[B,768]=[x|h], aw0[256,768], aw1[256,256], wcat[2048,768]=[w_ih|w_hh], ow0[512,512]
__global__ void __launch_bounds__(256) prep_kernel(
        const float* __restrict__ x, const float* __restrict__ h,
        const float* __restrict__ aw0, const float* __restrict__ aw1,
        const float* __restrict__ w_ih, const float* __restrict__ w_hh,
        const float* __restrict__ ow0,
        ushort* __restrict__ xh, ushort* __restrict__ baw0,
        ushort* __restrict__ baw1, ushort* __restrict__ wcat,
        ushort* __restrict__ bow0) {
    int idx = (blockIdx.x * 256 + threadIdx.x) * 4;
    const int N_XH = BROWS * KCAT;      // 6291456
    const int N_AW0 = IDIM * KCAT;      // 196608
    const int N_AW1 = IDIM * IDIM;      // 65536
    const int N_WCAT = G4 * KCAT;       // 1572864
    const int N_OW0 = HDIM * HDIM;      // 262144
    float4 v;
    ushort* dst;
    if (idx < N_XH) {
        int b = idx / KCAT, k = idx - b * KCAT;
        v = (k < IDIM) ? *(const float4*)&x[b * IDIM + k]
                       : *(const float4*)&h[b * HDIM + (k - IDIM)];
        dst = &xh[idx];
    } else if ((idx -= N_XH) < N_AW0) {
        v = *(const float4*)&aw0[idx]; dst = &baw0[idx];
    } else if ((idx -= N_AW0) < N_AW1) {
        v = *(const float4*)&aw1[idx]; dst = &baw1[idx];
    } else if ((idx -= N_AW1) < N_WCAT) {
        int o = idx / KCAT, k = idx - o * KCAT;
        v = (k < IDIM) ? *(const float4*)&w_ih[o * IDIM + k]
                       : *(const float4*)&w_hh[o * HDIM + (k - IDIM)];
        dst = &wcat[idx];
    } else if ((idx -= N_WCAT) < N_OW0) {
        v = *(const float4*)&ow0[idx]; dst = &bow0[idx];
    } else {
        return;
    }
    ushort4 o4 = { f2bf(v.x), f2bf(v.y), f2bf(v.z), f2bf(v.w) };
    *(ushort4*)dst = o4;
}

// ---------------- staged GEMM template: C = act(A @ W^T + bias) ----------------
// 128x128 tile, BK=32, 4 waves (2x2), wave 64x64 with 4x4 fragments.
// RELU_BF16=1: relu -> bf16 out; =0: fp32 out.
template<int RELU_BF16>
__global__ void __launch_bounds__(256) staged_gemm(
        const ushort* __restrict__ A, const ushort* __restrict__ W,
        const float* __restrict__ bias, void* __restrict__ outp,
        int Kdim, int out_ld) {
    __shared__ ushort As[2][4096];
    __shared__ ushort Ws[2][4096];
    const int tid = threadIdx.x;
    const int lane = tid & 63, wave = tid >> 6;
    const int wm = wave >> 1, wn = wave & 1;
    const int r = lane & 15, g = lane >> 4;
    const int row0 = blockIdx.x * 128;
    const int col0 = blockIdx.y * 128;
    const int s_row = tid >> 2, s_ch = tid & 3;   // staging: row 0..63 (+64), 16B chunk 0..3

    const ushort* aBase = A + (size_t)(row0 + s_row) * Kdim + s_ch * 8;
    const ushort* wBase = W + (size_t)(col0 + s_row) * Kdim + s_ch * 8;
    const int step64 = 64 * Kdim;

    f32x4 acc[4][4] = {};

    auto stage = [&](int buf, int kk) {
        gld_lds16(aBase + kk,          &As[buf][wave * 512]);
        gld_lds16(aBase + kk + step64, &As[buf][2048 + wave * 512]);
        gld_lds16(wBase + kk,          &Ws[buf][wave * 512]);
        gld_lds16(wBase + kk + step64, &Ws[buf][2048 + wave * 512]);
    };
    auto compute = [&](int buf) {
        bf16x8 af[4], wf[4];
#pragma unroll
        for (int t = 0; t < 4; t++)
            af[t] = *(const bf16x8*)&As[buf][(wm * 64 + t * 16 + r) * 32 + g * 8];
#pragma unroll
        for (int t = 0; t < 4; t++)
            wf[t] = *(const bf16x8*)&Ws[buf][(wn * 64 + t * 16 + r) * 32 + g * 8];
#pragma unroll
        for (int m = 0; m < 4; m++)
#pragma unroll
            for (int n = 0; n < 4; n++)
                acc[m][n] = mfma16(af[m], wf[n], acc[m][n]);
    };

    stage(0, 0);
    __syncthreads();
    const int NT = Kdim >> 5;
    int cur = 0;
    for (int t = 0; t < NT - 1; t++) {
        stage(cur ^ 1, (t + 1) << 5);
        compute(cur);
        __syncthreads();
        cur ^= 1;
    }
    compute(cur);

#pragma unroll
    for (int n = 0; n < 4; n++) {
        int col = col0 + wn * 64 + n * 16 + r;
        float bv = bias[col];
#pragma unroll
        for (int m = 0; m < 4; m++) {
            int rbase = row0 + wm * 64 + m * 16 + g * 4;
#pragma unroll
            for (int reg = 0; reg < 4; reg++) {
                float v = acc[m][n][reg] + bv;
                if (RELU_BF16) {
                    v = v > 0.f ? v : 0.f;
                    ((ushort*)outp)[(size_t)(rbase + reg) * out_ld + col] = f2bf(v);
                } else {
                    ((float*)outp)[(size_t)(rbase + reg) * out_ld + col] = v;
                }
            }
        }
    }
}

// ---------------- rowwise softmax + attn out + x_att into xh ----------------
__global__ void __launch_bounds__(256) attn_softmax(
        const float* __restrict__ logits, const float* __restrict__ x,
        float* __restrict__ attn_out, ushort* __restrict__ xh) {
    const int wave = threadIdx.x >> 6, lane = threadIdx.x & 63;
    const int row = blockIdx.x * 4 + wave;
    float v[4];
    float m = -1e30f;
#pragma unroll
    for (int i = 0; i < 4; i++) {
        v[i] = logits[row * IDIM + i * 64 + lane];
        m = fmaxf(m, v[i]);
    }
#pragma unroll
    for (int s = 32; s; s >>= 1) m = fmaxf(m, __shfl_xor(m, s, 64));
    float sum = 0.f;
#pragma unroll
    for (int i = 0; i < 4; i++) { v[i] = __expf(v[i] - m); sum += v[i]; }
#pragma unroll
    for (int s = 32; s; s >>= 1) sum += __shfl_xor(sum, s, 64);
    float inv = 1.f / sum;
#pragma unroll
    for (int i = 0; i < 4; i++) {
        int idx = i * 64 + lane;
        float a = v[i] * inv;
        attn_out[row * IDIM + idx] = a;
        xh[row * KCAT + idx] = f2bf(x[row * IDIM + idx] * a);
    }
}

// ---------------- fused gates GEMM + LSTM epilogue (staged) ----------------
// gates = [x_att|h] @ [w_ih|w_hh]^T : M=8192, j=512, 4 gates, K=768.
// Block tile: 128 rows x (4 gates x 32 j). Column mapping puts gate index on
// the fragment index tn, so each lane's acc[m][0..3] = (i,f,g,o) for one (row,j):
//   cc in [0,128): gi = (cc>>4)&3, jj = (cc&15) + ((cc>>6)<<4); wrow = gi*512 + j0 + jj
__global__ void __launch_bounds__(256) gates_staged(
        const ushort* __restrict__ A, const ushort* __restrict__ W,
        const float* __restrict__ b_ih, const float* __restrict__ b_hh,
        const float* __restrict__ c_in,
        float* __restrict__ h_out, float* __restrict__ c_out,
        ushort* __restrict__ h_bf) {
    __shared__ ushort As[2][4096];
    __shared__ ushort Ws[2][4096];
    const int tid = threadIdx.x;
    const int lane = tid & 63, wave = tid >> 6;
    const int wm = wave >> 1, wn = wave & 1;
    const int r = lane & 15, g = lane >> 4;
    const int row0 = blockIdx.x * 128;
    const int j0 = blockIdx.y * 32;
    const int s_row = tid >> 2, s_ch = tid & 3;

    auto wrow = [&](int cc) {
        return ((cc >> 4) & 3) * HDIM + j0 + (cc & 15) + ((cc >> 6) << 4);
    };
    const ushort* aBase = A + (size_t)(row0 + s_row) * KCAT + s_ch * 8;
    const ushort* w0p = W + (size_t)wrow(s_row) * KCAT + s_ch * 8;
    const ushort* w1p = W + (size_t)wrow(s_row + 64) * KCAT + s_ch * 8;

    f32x4 acc[4][4] = {};

    auto stage = [&](int buf, int kk) {
        gld_lds16(aBase + kk,              &As[buf][wave * 512]);
        gld_lds16(aBase + kk + 64 * KCAT,  &As[buf][2048 + wave * 512]);
        gld_lds16(w0p + kk,                &Ws[buf][wave * 512]);
        gld_lds16(w1p + kk,                &Ws[buf][2048 + wave * 512]);
    };
    auto compute = [&](int buf) {
        bf16x8 af[4], wf[4];
#pragma unroll
        for (int t = 0; t < 4; t++)
            af[t] = *(const bf16x8*)&As[buf][(wm * 64 + t * 16 + r) * 32 + g * 8];
#pragma unroll
        for (int t = 0; t < 4; t++)
            wf[t] = *(const bf16x8*)&Ws[buf][(wn * 64 + t * 16 + r) * 32 + g * 8];
#pragma unroll
        for (int m = 0; m < 4; m++)
#pragma unroll
            for (int n = 0; n < 4; n++)
                acc[m][n] = mfma16(af[m], wf[n], acc[m][n]);
    };

    stage(0, 0);
    __syncthreads();
    const int NT = KCAT >> 5;   // 24
    int cur = 0;
    for (int t = 0; t < NT - 1; t++) {
        stage(cur ^ 1, (t + 1) << 5);
        compute(cur);
        __syncthreads();
        cur ^= 1;
    }
    compute(cur);

    // LSTM epilogue: lane-local. j fixed per lane; gate = fragment index n.
    const int j = j0 + wn * 16 + r;
    float bb[4];
#pragma unroll
    for (int n = 0; n < 4; n++) bb[n] = b_ih[n * HDIM + j] + b_hh[n * HDIM + j];
#pragma unroll
    for (int m = 0; m < 4; m++) {
        int rbase = row0 + wm * 64 + m * 16 + g * 4;
#pragma unroll
        for (int reg = 0; reg < 4; reg++) {
            int row = rbase + reg;
            float ig = sigmoidf_(acc[m][0][reg] + bb[0]);
            float fg = sigmoidf_(acc[m][1][reg] + bb[1]);
            float gg = tanhf_(acc[m][2][reg] + bb[2]);
            float og = sigmoidf_(acc[m][3][reg] + bb[3]);
            float cn = fg * c_in[(size_t)row * HDIM + j] + ig * gg;
            float hn = og * tanhf_(cn);
            c_out[(size_t)row * HDIM + j] = cn;
            h_out[(size_t)row * HDIM + j] = hn;
            h_bf[(size_t)row * HDIM + j] = f2bf(hn);
        }
    }
}

// ---------------- head GEMV: out = sigmoid(hrelu . ow1 + ob1) ----------------
// one wave per row; lane covers 8 cols.
__global__ void __launch_bounds__(256) head_gemv(
        const ushort* __restrict__ Hrelu, const float* __restrict__ ow1,
        const float* __restrict__ ob1, float* __restrict__ outp) {
    const int wave = threadIdx.x >> 6, lane = threadIdx.x & 63;
    const int row = blockIdx.x * 4 + wave;
    typedef ushort u16x8 __attribute__((ext_vector_type(8)));
    u16x8 hv = *(const u16x8*)&Hrelu[(size_t)row * HDIM + lane * 8];
    float4 w0 = *(const float4*)&ow1[lane * 8];
    float4 w1 = *(const float4*)&ow1[lane * 8 + 4];
    float s = bf2f(hv[0]) * w0.x + bf2f(hv[1]) * w0.y + bf2f(hv[2]) * w0.z +
              bf2f(hv[3]) * w0.w + bf2f(hv[4]) * w1.x + bf2f(hv[5]) * w1.y +
              bf2f(hv[6]) * w1.z + bf2f(hv[7]) * w1.w;
#pragma unroll
    for (int sh = 32; sh; sh >>= 1) s += __shfl_xor(s, sh, 64);
    if (lane == 0) outp[row] = 1.f / (1.f + __expf(-(s + ob1[0])));
}

extern "C" void kernel_launch(void* const* d_in, const int* in_sizes, int n_in,
                              void* d_out, int out_size, void* d_ws, size_t ws_size,
                              hipStream_t stream) {
    const float* x    = (const float*)d_in[0];
    const float* h    = (const float*)d_in[1];
    const float* c    = (const float*)d_in[2];
    const float* aw0  = (const float*)d_in[3];
    const float* ab0  = (const float*)d_in[4];
    const float* aw1  = (const float*)d_in[5];
    const float* ab1  = (const float*)d_in[6];
    const float* w_ih = (const float*)d_in[7];
    const float* b_ih = (const float*)d_in[8];
    const float* w_hh = (const float*)d_in[9];
    const float* b_hh = (const float*)d_in[10];
    const float* ow0  = (const float*)d_in[11];
    const float* ob0  = (const float*)d_in[12];
    const float* ow1  = (const float*)d_in[13];
    const float* ob1  = (const float*)d_in[14];

    char* ws = (char*)d_ws;
    ushort* xh     = (ushort*)(ws + 0);           // 8192*768*2  = 12582912
    ushort* a0     = (ushort*)(ws + 12582912);    // 8192*256*2  = 4194304
    float*  logits = (float*) (ws + 16777216);    // 8192*256*4  = 8388608
    ushort* hrelu  = (ushort*)(ws + 16777216);    // aliases logits (dead after softmax)
    ushort* hbf    = (ushort*)(ws + 25165824);    // 8192*512*2  = 8388608
    ushort* baw0   = (ushort*)(ws + 33554432);    // 256*768*2   = 393216
    ushort* baw1   = (ushort*)(ws + 33947648);    // 256*256*2   = 131072
    ushort* wcat   = (ushort*)(ws + 34078720);    // 2048*768*2  = 3145728
    ushort* bow0   = (ushort*)(ws + 37224448);    // 512*512*2   = 524288
    // total ws use: 37748736 bytes

    float* outv    = (float*)d_out;               // [8192]
    float* h_out   = outv + 8192;                 // [8192,512]
    float* c_out   = outv + 4202496;              // [8192,512]
    float* attn_o  = outv + 8396800;              // [8192,256]

    prep_kernel<<<8192, 256, 0, stream>>>(x, h, aw0, aw1, w_ih, w_hh, ow0,
                                          xh, baw0, baw1, wcat, bow0);
    // a0 = relu(xh @ aw0^T + ab0)         M=8192 N=256 K=768
    staged_gemm<1><<<dim3(64, 2), 256, 0, stream>>>(xh, baw0, ab0, a0, KCAT, IDIM);
    // logits = a0 @ aw1^T + ab1           M=8192 N=256 K=256
    staged_gemm<0><<<dim3(64, 2), 256, 0, stream>>>(a0, baw1, ab1, logits, IDIM, IDIM);
    attn_softmax<<<2048, 256, 0, stream>>>(logits, x, attn_o, xh);
    // fused LSTM gates                    M=8192 N=2048 K=768
    gates_staged<<<dim3(64, 16), 256, 0, stream>>>(xh, wcat, b_ih, b_hh, c,
                                                   h_out, c_out, hbf);
    // hrelu = relu(h_new @ ow0^T + ob0)   M=8192 N=512 K=512
    staged_gemm<1><<<dim3(64, 4), 256, 0, stream>>>(hbf, bow0, ob0, hrelu, HDIM, HDIM);
    head_gemv<<<2048, 256, 0, stream>>>(hrelu, ow1, ob1, outv);
}